// Round 1
// baseline (331.212 us; speedup 1.0000x reference)
//
#include <hip/hip_runtime.h>
#include <hip/hip_bf16.h>

// ---------- types ----------
typedef __attribute__((ext_vector_type(8))) short s16x8;
typedef __attribute__((ext_vector_type(4))) short s16x4;
typedef __attribute__((ext_vector_type(4))) float f32x4;

__device__ __forceinline__ float b2f(short s) {
  return __uint_as_float(((unsigned)(unsigned short)s) << 16);
}
__device__ __forceinline__ short f2b(float f) {
  unsigned u = __float_as_uint(f);
  unsigned r = u + 0x7fffu + ((u >> 16) & 1u);   // round-to-nearest-even
  return (short)(r >> 16);
}

// ---------- problem constants ----------
#define BATCH 64
#define NP    196
#define TL    77
#define DM    512
#define CIMG  1024

// ---------- weight transpose+cast: W[K][512] f32 -> WT[512][K] bf16 ----------
__global__ __launch_bounds__(256)
void wtrans_kernel(const float* __restrict__ Wi, const float* __restrict__ Wt,
                   const float* __restrict__ Wq, const float* __restrict__ Wk,
                   const float* __restrict__ Wv, const float* __restrict__ Wo,
                   short* __restrict__ WiT, short* __restrict__ WtT,
                   short* __restrict__ WqT, short* __restrict__ WkT,
                   short* __restrict__ WvT, short* __restrict__ WoT) {
  int z = blockIdx.z;
  const float* W; short* WT; int K;
  switch (z) {
    case 0: W = Wi; WT = WiT; K = 1024; break;
    case 1: W = Wt; WT = WtT; K = 1024; break;
    case 2: W = Wq; WT = WqT; K = 512;  break;
    case 3: W = Wk; WT = WkT; K = 512;  break;
    case 4: W = Wv; WT = WvT; K = 512;  break;
    default: W = Wo; WT = WoT; K = 512; break;
  }
  int k0 = blockIdx.x * 32, n0 = blockIdx.y * 32;
  if (k0 >= K) return;
  __shared__ float tile[32][33];
  int tx = threadIdx.x & 31, ty = threadIdx.x >> 5;   // ty 0..7
  #pragma unroll
  for (int i = 0; i < 4; i++) {
    int k = k0 + ty + i * 8;
    tile[ty + i * 8][tx] = W[(size_t)k * 512 + n0 + tx];
  }
  __syncthreads();
  #pragma unroll
  for (int i = 0; i < 4; i++) {
    int n = n0 + ty + i * 8;
    WT[(size_t)n * K + k0 + tx] = f2b(tile[tx][ty + i * 8]);
  }
}

// ---------- f32 -> bf16 cast (vectorized) ----------
__global__ void cast_f32_bf16(const float* __restrict__ in, short* __restrict__ out, int n4) {
  int stride = gridDim.x * blockDim.x;
  for (int i = blockIdx.x * blockDim.x + threadIdx.x; i < n4; i += stride) {
    float4 v = ((const float4*)in)[i];
    s16x4 o;
    o[0] = f2b(v.x); o[1] = f2b(v.y); o[2] = f2b(v.z); o[3] = f2b(v.w);
    ((s16x4*)out)[i] = o;
  }
}

// ---------- image transpose: [64][1024][196] f32 -> [64][196][1024] bf16 ----------
__global__ __launch_bounds__(256)
void img_trans(const float* __restrict__ img, short* __restrict__ out) {
  int b = blockIdx.z;
  int c0 = blockIdx.x * 32;   // channel tile
  int n0 = blockIdx.y * 32;   // patch tile (0..192)
  __shared__ float tile[32][33];
  int tx = threadIdx.x & 31, ty = threadIdx.x >> 5;
  const float* ib = img + (size_t)b * CIMG * NP;
  #pragma unroll
  for (int i = 0; i < 4; i++) {
    int c = c0 + ty + i * 8, n = n0 + tx;
    tile[ty + i * 8][tx] = (n < NP) ? ib[(size_t)c * NP + n] : 0.f;
  }
  __syncthreads();
  short* ob = out + (size_t)b * NP * CIMG;
  #pragma unroll
  for (int i = 0; i < 4; i++) {
    int n = n0 + ty + i * 8;
    if (n < NP) ob[(size_t)n * CIMG + c0 + tx] = f2b(tile[tx][ty + i * 8]);
  }
}

// ---------- MFMA GEMM: C[M,512] = A[M,K](bf16) x BT[512,K](bf16)^T + bias ----------
// 128x128 tile, 4 waves (each 64x64 = 4x4 MFMA frags), BK=32, single-buffered.
__global__ __launch_bounds__(256)
void gemm_bt(const short* __restrict__ A, const short* __restrict__ BT,
             const float* __restrict__ bias,
             float* __restrict__ outF, short* __restrict__ outB,
             int M, int K) {
  const int N = 512;
  __shared__ short As[128 * 40];   // pad 32->40 elems (80B stride: bank-spread)
  __shared__ short Bs[128 * 40];
  int bm = blockIdx.x * 128, bn = blockIdx.y * 128;
  int tid = threadIdx.x;
  int wave = tid >> 6, lane = tid & 63;
  int wr = (wave >> 1) * 64, wc = (wave & 1) * 64;
  int r = lane & 15, kg = lane >> 4;
  f32x4 acc[4][4];
  #pragma unroll
  for (int i = 0; i < 4; i++)
    #pragma unroll
    for (int j = 0; j < 4; j++) acc[i][j] = (f32x4){0.f, 0.f, 0.f, 0.f};

  for (int k0 = 0; k0 < K; k0 += 32) {
    #pragma unroll
    for (int i = 0; i < 2; i++) {
      int idx = tid + i * 256;          // 0..511
      int row = idx >> 2;               // 0..127
      int col = (idx & 3) << 3;         // 0,8,16,24
      int ar = bm + row; if (ar > M - 1) ar = M - 1;   // clamp (rows guarded at store)
      *(s16x8*)&As[row * 40 + col] = *(const s16x8*)&A[(size_t)ar * K + k0 + col];
      *(s16x8*)&Bs[row * 40 + col] = *(const s16x8*)&BT[(size_t)(bn + row) * K + k0 + col];
    }
    __syncthreads();
    s16x8 af[4], bf[4];
    #pragma unroll
    for (int i = 0; i < 4; i++) af[i] = *(const s16x8*)&As[(wr + i * 16 + r) * 40 + kg * 8];
    #pragma unroll
    for (int j = 0; j < 4; j++) bf[j] = *(const s16x8*)&Bs[(wc + j * 16 + r) * 40 + kg * 8];
    #pragma unroll
    for (int i = 0; i < 4; i++)
      #pragma unroll
      for (int j = 0; j < 4; j++)
        acc[i][j] = __builtin_amdgcn_mfma_f32_16x16x32_bf16(af[i], bf[j], acc[i][j], 0, 0, 0);
    __syncthreads();
  }
  // epilogue: C/D layout col=lane&15, row=(lane>>4)*4+reg  [verified m89/m91]
  #pragma unroll
  for (int i = 0; i < 4; i++) {
    #pragma unroll
    for (int rr = 0; rr < 4; rr++) {
      int row = bm + wr + i * 16 + kg * 4 + rr;
      if (row < M) {
        #pragma unroll
        for (int j = 0; j < 4; j++) {
          int col = bn + wc + j * 16 + r;
          float v = acc[i][j][rr] + bias[col];
          if (outF) outF[(size_t)row * N + col] = v;
          if (outB) outB[(size_t)row * N + col] = f2b(v);
        }
      }
    }
  }
}

// ---------- attention: one block per (b,h) ----------
__global__ __launch_bounds__(256)
void attn_kernel(const short* __restrict__ qB, const short* __restrict__ kB,
                 const short* __restrict__ vB, short* __restrict__ attnB,
                 short* __restrict__ w_all) {
  __shared__ float kls[TL * 64];
  __shared__ float vls[TL * 64];
  __shared__ short wls[NP * 80];
  int bh = blockIdx.x, b = bh >> 3, h = bh & 7;
  int tid = threadIdx.x;
  // stage K,V (bf16 -> f32)
  for (int idx = tid; idx < TL * 8; idx += 256) {
    int t = idx >> 3, c = (idx & 7) << 3;
    size_t g = ((size_t)(b * TL + t)) * DM + h * 64 + c;
    s16x8 kv = *(const s16x8*)&kB[g];
    s16x8 vv = *(const s16x8*)&vB[g];
    f32x4 a0, a1, b0, b1;
    #pragma unroll
    for (int j = 0; j < 4; j++) { a0[j] = b2f(kv[j]); a1[j] = b2f(kv[j + 4]); }
    #pragma unroll
    for (int j = 0; j < 4; j++) { b0[j] = b2f(vv[j]); b1[j] = b2f(vv[j + 4]); }
    *(f32x4*)&kls[t * 64 + c] = a0; *(f32x4*)&kls[t * 64 + c + 4] = a1;
    *(f32x4*)&vls[t * 64 + c] = b0; *(f32x4*)&vls[t * 64 + c + 4] = b1;
  }
  __syncthreads();
  if (tid < NP) {
    int n = tid;
    float qf[64];
    const short* qrow = qB + ((size_t)(b * NP + n)) * DM + h * 64;
    #pragma unroll
    for (int c = 0; c < 8; c++) {
      s16x8 qv = *(const s16x8*)(qrow + c * 8);
      #pragma unroll
      for (int j = 0; j < 8; j++) qf[c * 8 + j] = b2f(qv[j]);
    }
    for (int t2 = 0; t2 < TL; t2++) {           // raw scores -> wls (bf16)
      float s = 0.f;
      #pragma unroll
      for (int c = 0; c < 64; c += 4) {
        f32x4 kv = *(const f32x4*)&kls[t2 * 64 + c];
        s += qf[c] * kv[0] + qf[c + 1] * kv[1] + qf[c + 2] * kv[2] + qf[c + 3] * kv[3];
      }
      wls[n * 80 + t2] = f2b(s * 0.125f);       // * hd^-0.5
    }
    float m = -1e30f;
    for (int t2 = 0; t2 < TL; t2++) m = fmaxf(m, b2f(wls[n * 80 + t2]));
    float sum = 0.f;
    for (int t2 = 0; t2 < TL; t2++) {
      float e = __expf(b2f(wls[n * 80 + t2]) - m);
      sum += e;
      wls[n * 80 + t2] = f2b(e);
    }
    float rinv = 1.f / sum;
    short* wrow = w_all + ((size_t)bh * NP + n) * TL;
    for (int t2 = 0; t2 < TL; t2++) {
      short wb = f2b(b2f(wls[n * 80 + t2]) * rinv);
      wls[n * 80 + t2] = wb;
      wrow[t2] = wb;
    }
  }
  __syncthreads();
  // PV: task = (n, d-chunk of 8)
  for (int task = tid; task < NP * 8; task += 256) {
    int n = task >> 3, d8 = (task & 7) << 3;
    float acc[8] = {0, 0, 0, 0, 0, 0, 0, 0};
    for (int t2 = 0; t2 < TL; t2++) {
      float w = b2f(wls[n * 80 + t2]);
      f32x4 v0 = *(const f32x4*)&vls[t2 * 64 + d8];
      f32x4 v1 = *(const f32x4*)&vls[t2 * 64 + d8 + 4];
      acc[0] += w * v0[0]; acc[1] += w * v0[1]; acc[2] += w * v0[2]; acc[3] += w * v0[3];
      acc[4] += w * v1[0]; acc[5] += w * v1[1]; acc[6] += w * v1[2]; acc[7] += w * v1[3];
    }
    s16x8 o;
    #pragma unroll
    for (int j = 0; j < 8; j++) o[j] = f2b(acc[j]);
    *(s16x8*)&attnB[((size_t)(b * NP + n)) * DM + h * 64 + d8] = o;
  }
}

// ---------- mean over heads of attention weights ----------
__global__ void meanw_kernel(const short* __restrict__ w_all, float* __restrict__ outW) {
  int i = blockIdx.x * 256 + threadIdx.x;
  if (i >= BATCH * NP * TL) return;
  int b = i / (NP * TL);
  int r = i - b * (NP * TL);
  float s = 0.f;
  #pragma unroll
  for (int h = 0; h < 8; h++) s += b2f(w_all[((size_t)(b * 8 + h)) * (NP * TL) + r]);
  outW[i] = s * 0.125f;
}

// ---------- means over rows + l2 normalize ----------
__global__ __launch_bounds__(256)
void avgcls_kernel(const float* __restrict__ attn_out, const float* __restrict__ proj_txt,
                   float* __restrict__ outAvg, float* __restrict__ outCls,
                   float* __restrict__ normA, float* __restrict__ normC) {
  int b = blockIdx.x & 63;
  bool isCls = blockIdx.x >= 64;
  const float* src = isCls ? (proj_txt + (size_t)b * TL * DM) : (attn_out + (size_t)b * NP * DM);
  int rows = isCls ? TL : NP;
  int tid = threadIdx.x;
  int c0 = tid * 2;
  float s0 = 0.f, s1 = 0.f;
  for (int rI = 0; rI < rows; rI++) {
    s0 += src[(size_t)rI * DM + c0];
    s1 += src[(size_t)rI * DM + c0 + 1];
  }
  float inv = 1.f / (float)rows;
  s0 *= inv; s1 *= inv;
  float sq = s0 * s0 + s1 * s1;
  #pragma unroll
  for (int off = 32; off > 0; off >>= 1) sq += __shfl_down(sq, off, 64);
  __shared__ float redL[4];
  __shared__ float rnS;
  int wave = tid >> 6, lane = tid & 63;
  if (lane == 0) redL[wave] = sq;
  __syncthreads();
  if (tid == 0) {
    float tot = redL[0] + redL[1] + redL[2] + redL[3];
    rnS = 1.f / fmaxf(sqrtf(tot), 1e-8f);
  }
  __syncthreads();
  float rn = rnS;
  float* om = isCls ? outCls : outAvg;
  float* on = isCls ? normC : normA;
  om[(size_t)b * DM + c0] = s0;      om[(size_t)b * DM + c0 + 1] = s1;
  on[(size_t)b * DM + c0] = s0 * rn; on[(size_t)b * DM + c0 + 1] = s1 * rn;
}

// ---------- cosine similarity matrix 64x64 ----------
__global__ __launch_bounds__(256)
void score_kernel(const float* __restrict__ normA, const float* __restrict__ normC,
                  float* __restrict__ outScore) {
  int i = blockIdx.x;   // 0..63
  __shared__ float als[DM];
  __shared__ float part[256];
  for (int c = threadIdx.x; c < DM; c += 256) als[c] = normA[(size_t)i * DM + c];
  __syncthreads();
  int j = threadIdx.x & 63;
  int ch = threadIdx.x >> 6;   // 0..3
  float s = 0.f;
  for (int c = ch * 128; c < ch * 128 + 128; c++) s += als[c] * normC[(size_t)j * DM + c];
  part[threadIdx.x] = s;
  __syncthreads();
  if (threadIdx.x < 64) {
    outScore[(size_t)i * 64 + j] = part[j] + part[64 + j] + part[128 + j] + part[192 + j];
  }
}

// ---------- launcher ----------
extern "C" void kernel_launch(void* const* d_in, const int* in_sizes, int n_in,
                              void* d_out, int out_size, void* d_ws, size_t ws_size,
                              hipStream_t stream) {
  (void)in_sizes; (void)n_in; (void)out_size; (void)ws_size;
  const float* img = (const float*)d_in[0];
  const float* txt = (const float*)d_in[1];
  const float* Wi  = (const float*)d_in[2];
  const float* bi  = (const float*)d_in[3];
  const float* Wt  = (const float*)d_in[4];
  const float* bt  = (const float*)d_in[5];
  const float* Wq  = (const float*)d_in[6];
  const float* bq  = (const float*)d_in[7];
  const float* Wk  = (const float*)d_in[8];
  const float* bk  = (const float*)d_in[9];
  const float* Wv  = (const float*)d_in[10];
  const float* bv  = (const float*)d_in[11];
  const float* Wo  = (const float*)d_in[12];
  const float* bo  = (const float*)d_in[13];
  float* out = (float*)d_out;

  // workspace layout (bytes)
  constexpr size_t MI = (size_t)BATCH * NP;   // 12544
  constexpr size_t MT = (size_t)BATCH * TL;   // 4928
  constexpr size_t SZ_AIMG  = MI * 1024 * 2;  // 25,690,112
  constexpr size_t SZ_TEXTB = MT * 1024 * 2;  // 10,092,544
  constexpr size_t SZ_PIMGB = MI * 512 * 2;   // 12,845,056
  constexpr size_t SZ_PTXTB = MT * 512 * 2;   //  5,046,272
  constexpr size_t SZ_WALL  = (size_t)BATCH * 8 * NP * TL * 2;
  constexpr size_t O_AIMG  = 0;
  constexpr size_t O_TEXTB = O_AIMG + SZ_AIMG;
  constexpr size_t O_PIMGB = O_TEXTB + SZ_TEXTB;
  constexpr size_t O_PTXTB = O_PIMGB + SZ_PIMGB;
  constexpr size_t O_WALL  = O_PTXTB + SZ_PTXTB;
  constexpr size_t O_WIT   = O_WALL + SZ_WALL;
  constexpr size_t O_WTT   = O_WIT + 1024 * 512 * 2;
  constexpr size_t O_WQT   = O_WTT + 1024 * 512 * 2;
  constexpr size_t O_WKT   = O_WQT + 512 * 512 * 2;
  constexpr size_t O_WVT   = O_WKT + 512 * 512 * 2;
  constexpr size_t O_WOT   = O_WVT + 512 * 512 * 2;
  constexpr size_t O_NA    = O_WOT + 512 * 512 * 2;
  constexpr size_t O_NC    = O_NA + (size_t)BATCH * DM * 4;

  char* ws = (char*)d_ws;
  short* aimg  = (short*)(ws + O_AIMG);
  short* textB = (short*)(ws + O_TEXTB);
  short* kBuf  = textB;                                   // alias (textB dead)
  short* vBuf  = (short*)(ws + O_TEXTB + SZ_PTXTB);
  short* pimgB = (short*)(ws + O_PIMGB);
  short* attnB = pimgB;                                   // alias (pimgB dead)
  short* ptxtB = (short*)(ws + O_PTXTB);
  short* wAll  = (short*)(ws + O_WALL);
  short* wit   = (short*)(ws + O_WIT);
  short* wtt   = (short*)(ws + O_WTT);
  short* wqt   = (short*)(ws + O_WQT);
  short* wkt   = (short*)(ws + O_WKT);
  short* wvt   = (short*)(ws + O_WVT);
  short* wot   = (short*)(ws + O_WOT);
  float* normA = (float*)(ws + O_NA);
  float* normC = (float*)(ws + O_NC);
  short* qBuf  = aimg;                                    // alias (aimg dead)

  // output layout (floats)
  float* oScore = out;                                    // 64*64
  float* oAttn  = out + 4096;                             // 64*196*512
  float* oW     = oAttn + MI * 512;                       // 64*196*77
  float* oAvg   = oW + (size_t)BATCH * NP * TL;           // 64*512
  float* oCls   = oAvg + (size_t)BATCH * DM;              // 64*512
  float* oPtxt  = oCls + (size_t)BATCH * DM;              // 64*77*512

  wtrans_kernel<<<dim3(32, 16, 6), 256, 0, stream>>>(Wi, Wt, Wq, Wk, Wv, Wo,
                                                     wit, wtt, wqt, wkt, wvt, wot);
  cast_f32_bf16<<<dim3(1024), 256, 0, stream>>>(txt, textB, (int)(MT * 1024 / 4));
  img_trans<<<dim3(32, 7, 64), 256, 0, stream>>>(img, aimg);

  gemm_bt<<<dim3(39, 4), 256, 0, stream>>>(textB, wtt, bt, oPtxt, ptxtB, (int)MT, 1024);
  gemm_bt<<<dim3(98, 4), 256, 0, stream>>>(aimg, wit, bi, nullptr, pimgB, (int)MI, 1024);
  gemm_bt<<<dim3(39, 4), 256, 0, stream>>>(ptxtB, wkt, bk, nullptr, kBuf, (int)MT, 512);
  gemm_bt<<<dim3(39, 4), 256, 0, stream>>>(ptxtB, wvt, bv, nullptr, vBuf, (int)MT, 512);
  gemm_bt<<<dim3(98, 4), 256, 0, stream>>>(pimgB, wqt, bq, nullptr, qBuf, (int)MI, 512);

  attn_kernel<<<dim3(512), 256, 0, stream>>>(qBuf, kBuf, vBuf, attnB, wAll);
  meanw_kernel<<<dim3((BATCH * NP * TL + 255) / 256), 256, 0, stream>>>(wAll, oW);

  gemm_bt<<<dim3(98, 4), 256, 0, stream>>>(attnB, wot, bo, oAttn, nullptr, (int)MI, 512);

  avgcls_kernel<<<dim3(128), 256, 0, stream>>>(oAttn, oPtxt, oAvg, oCls, normA, normC);
  score_kernel<<<dim3(64), 256, 0, stream>>>(normA, normC, oScore);
}

// Round 2
// 240.576 us; speedup vs baseline: 1.3767x; 1.3767x over previous
//
#include <hip/hip_runtime.h>
#include <hip/hip_bf16.h>

// ---------- types ----------
typedef __attribute__((ext_vector_type(8))) short s16x8;
typedef __attribute__((ext_vector_type(4))) short s16x4;
typedef __attribute__((ext_vector_type(4))) float f32x4;

__device__ __forceinline__ float b2f(short s) {
  return __uint_as_float(((unsigned)(unsigned short)s) << 16);
}
__device__ __forceinline__ short f2b(float f) {
  unsigned u = __float_as_uint(f);
  unsigned r = u + 0x7fffu + ((u >> 16) & 1u);   // round-to-nearest-even
  return (short)(r >> 16);
}

// async global->LDS, 16B per lane; LDS dest = wave-uniform base + lane*16
__device__ __forceinline__ void gload16(const short* g, short* l) {
  __builtin_amdgcn_global_load_lds((const __attribute__((address_space(1))) void*)g,
                                   (__attribute__((address_space(3))) void*)l, 16, 0, 0);
}

// ---------- problem constants ----------
#define BATCH 64
#define NP    196
#define TL    77
#define DM    512
#define CIMG  1024

// ---------- weight transpose+cast: W[K][512] f32 -> WT[512][K] bf16 ----------
__global__ __launch_bounds__(256)
void wtrans_kernel(const float* __restrict__ Wi, const float* __restrict__ Wt,
                   const float* __restrict__ Wq, const float* __restrict__ Wk,
                   const float* __restrict__ Wv, const float* __restrict__ Wo,
                   short* __restrict__ WiT, short* __restrict__ WtT,
                   short* __restrict__ WqT, short* __restrict__ WkT,
                   short* __restrict__ WvT, short* __restrict__ WoT) {
  int z = blockIdx.z;
  const float* W; short* WT; int K;
  switch (z) {
    case 0: W = Wi; WT = WiT; K = 1024; break;
    case 1: W = Wt; WT = WtT; K = 1024; break;
    case 2: W = Wq; WT = WqT; K = 512;  break;
    case 3: W = Wk; WT = WkT; K = 512;  break;
    case 4: W = Wv; WT = WvT; K = 512;  break;
    default: W = Wo; WT = WoT; K = 512; break;
  }
  int k0 = blockIdx.x * 32, n0 = blockIdx.y * 32;
  if (k0 >= K) return;
  __shared__ float tile[32][33];
  int tx = threadIdx.x & 31, ty = threadIdx.x >> 5;   // ty 0..7
  #pragma unroll
  for (int i = 0; i < 4; i++) {
    int k = k0 + ty + i * 8;
    tile[ty + i * 8][tx] = W[(size_t)k * 512 + n0 + tx];
  }
  __syncthreads();
  #pragma unroll
  for (int i = 0; i < 4; i++) {
    int n = n0 + ty + i * 8;
    WT[(size_t)n * K + k0 + tx] = f2b(tile[tx][ty + i * 8]);
  }
}

// ---------- f32 -> bf16 cast (vectorized) ----------
__global__ void cast_f32_bf16(const float* __restrict__ in, short* __restrict__ out, int n4) {
  int stride = gridDim.x * blockDim.x;
  for (int i = blockIdx.x * blockDim.x + threadIdx.x; i < n4; i += stride) {
    float4 v = ((const float4*)in)[i];
    s16x4 o;
    o[0] = f2b(v.x); o[1] = f2b(v.y); o[2] = f2b(v.z); o[3] = f2b(v.w);
    ((s16x4*)out)[i] = o;
  }
}

// ---------- image transpose: [64][1024][196] f32 -> [64][196][1024] bf16 ----------
__global__ __launch_bounds__(256)
void img_trans(const float* __restrict__ img, short* __restrict__ out) {
  int b = blockIdx.z;
  int c0 = blockIdx.x * 32;
  int n0 = blockIdx.y * 32;
  __shared__ float tile[32][33];
  int tx = threadIdx.x & 31, ty = threadIdx.x >> 5;
  const float* ib = img + (size_t)b * CIMG * NP;
  #pragma unroll
  for (int i = 0; i < 4; i++) {
    int c = c0 + ty + i * 8, n = n0 + tx;
    tile[ty + i * 8][tx] = (n < NP) ? ib[(size_t)c * NP + n] : 0.f;
  }
  __syncthreads();
  short* ob = out + (size_t)b * NP * CIMG;
  #pragma unroll
  for (int i = 0; i < 4; i++) {
    int n = n0 + ty + i * 8;
    if (n < NP) ob[(size_t)n * CIMG + c0 + tx] = f2b(tile[tx][ty + i * 8]);
  }
}

// ---------- MFMA GEMM (m97 structure): C[M,N] = A[M,K] x BT[N,K]^T + bias ----------
// 128x128 tile, 4 waves, BK=32, global_load_lds staging, linear LDS [128][32].
__global__ __launch_bounds__(256)
void gemm_bt(const short* __restrict__ A, const short* __restrict__ BT,
             const float* __restrict__ bias, const float* __restrict__ bias2,
             float* __restrict__ outF, short* __restrict__ outB,
             int M, int K, int N) {
  __shared__ short As[128 * 32];
  __shared__ short Bs[128 * 32];
  int bm = blockIdx.x * 128, bn = blockIdx.y * 128;
  int tid = threadIdx.x;
  int wave = tid >> 6, lane = tid & 63;
  int wr = (wave >> 1) * 64, wc = (wave & 1) * 64;
  int r = lane & 15, kg = lane >> 4;

  // staging source: wave w covers rows w*32..w*32+31 (2 instrs of 16 rows)
  int srow = wave * 32 + (lane >> 2);
  int scol = (lane & 3) * 8;
  int ar0 = bm + srow;      if (ar0 > M - 1) ar0 = M - 1;
  int ar1 = bm + srow + 16; if (ar1 > M - 1) ar1 = M - 1;
  const short* ga0 = A + (size_t)ar0 * K + scol;
  const short* ga1 = A + (size_t)ar1 * K + scol;
  const short* gb0 = BT + (size_t)(bn + srow) * K + scol;
  const short* gb1 = BT + (size_t)(bn + srow + 16) * K + scol;
  short* lA0 = &As[(wave * 32) * 32];
  short* lA1 = &As[(wave * 32 + 16) * 32];
  short* lB0 = &Bs[(wave * 32) * 32];
  short* lB1 = &Bs[(wave * 32 + 16) * 32];

  f32x4 acc[4][4];
  #pragma unroll
  for (int i = 0; i < 4; i++)
    #pragma unroll
    for (int j = 0; j < 4; j++) acc[i][j] = (f32x4){0.f, 0.f, 0.f, 0.f};

  for (int k0 = 0; k0 < K; k0 += 32) {
    gload16(ga0 + k0, lA0);
    gload16(ga1 + k0, lA1);
    gload16(gb0 + k0, lB0);
    gload16(gb1 + k0, lB1);
    __syncthreads();                       // compiler drains vmcnt(0) here
    s16x8 af[4], bf[4];
    #pragma unroll
    for (int i = 0; i < 4; i++) af[i] = *(const s16x8*)&As[(wr + i * 16 + r) * 32 + kg * 8];
    #pragma unroll
    for (int j = 0; j < 4; j++) bf[j] = *(const s16x8*)&Bs[(wc + j * 16 + r) * 32 + kg * 8];
    #pragma unroll
    for (int i = 0; i < 4; i++)
      #pragma unroll
      for (int j = 0; j < 4; j++)
        acc[i][j] = __builtin_amdgcn_mfma_f32_16x16x32_bf16(af[i], bf[j], acc[i][j], 0, 0, 0);
    __syncthreads();
  }
  // epilogue: C/D layout col=lane&15, row=(lane>>4)*4+reg
  #pragma unroll
  for (int i = 0; i < 4; i++) {
    #pragma unroll
    for (int rr = 0; rr < 4; rr++) {
      int row = bm + wr + i * 16 + kg * 4 + rr;
      if (row < M) {
        #pragma unroll
        for (int j = 0; j < 4; j++) {
          int col = bn + wc + j * 16 + r;
          float bval = (col < 512) ? bias[col] : bias2[col - 512];
          float v = acc[i][j][rr] + bval;
          if (outF) outF[(size_t)row * N + col] = v;
          if (outB) outB[(size_t)row * N + col] = f2b(v);
        }
      }
    }
  }
}

// ---------- MFMA attention: one block per (b,h), 4 waves ----------
// kvB layout: [B*TL][1024] bf16, cols 0..511 = k, 512..1023 = v
__global__ __launch_bounds__(256)
void attn_kernel(const short* __restrict__ qB, const short* __restrict__ kvB,
                 short* __restrict__ attnB, short* __restrict__ wAll) {
  __shared__ short kls[80 * 72];        // K rows padded to 80, stride 72 (2-way)
  __shared__ short vtls[64 * 104];      // V^T [d][t], t<96 used, stride 104 (2-way)
  __shared__ short pls[4][16 * 104];    // per-wave P tile [16 rows][t]
  int bh = blockIdx.x, b = bh >> 3, h = bh & 7;
  int tid = threadIdx.x, wave = tid >> 6, lane = tid & 63;
  int r = lane & 15, kg = lane >> 4;

  // zero pls (cols 80..95 must stay zero for PV K-padding)
  for (int i = lane; i < 208; i += 64)
    *(s16x8*)&pls[wave][i * 8] = (s16x8){0, 0, 0, 0, 0, 0, 0, 0};

  // stage K -> kls (rows >=77 zero)
  for (int idx = tid; idx < 80 * 8; idx += 256) {
    int t = idx >> 3, c8 = (idx & 7) << 3;
    s16x8 v = (s16x8){0, 0, 0, 0, 0, 0, 0, 0};
    if (t < 77) v = *(const s16x8*)&kvB[((size_t)(b * TL + t)) * 1024 + h * 64 + c8];
    *(s16x8*)&kls[t * 72 + c8] = v;
  }
  // stage V^T -> vtls[d][t] (t>=77 zero); coalesced global reads per (t,j)
  for (int idx = tid; idx < 64 * 12; idx += 256) {
    int d = idx & 63, t8 = idx >> 6;    // t8 0..11 covers t<96
    s16x8 v;
    #pragma unroll
    for (int j = 0; j < 8; j++) {
      int t = t8 * 8 + j;
      v[j] = (t < 77) ? kvB[((size_t)(b * TL + t)) * 1024 + 512 + h * 64 + d] : (short)0;
    }
    *(s16x8*)&vtls[d * 104 + t8 * 8] = v;
  }
  __syncthreads();

  // V B-fragments in registers (reused across m-frags)
  s16x8 vf[4][3];
  #pragma unroll
  for (int jd = 0; jd < 4; jd++)
    #pragma unroll
    for (int kk = 0; kk < 3; kk++)
      vf[jd][kk] = *(const s16x8*)&vtls[(jd * 16 + r) * 104 + kg * 8 + kk * 32];

  for (int mf = wave; mf < 13; mf += 4) {
    int m0 = mf * 16;
    int qrow = m0 + r; if (qrow > 195) qrow = 195;
    const short* qp = qB + ((size_t)(b * NP + qrow)) * 512 + h * 64 + kg * 8;
    s16x8 qf0 = *(const s16x8*)qp;
    s16x8 qf1 = *(const s16x8*)(qp + 32);

    f32x4 s[5];
    #pragma unroll
    for (int j = 0; j < 5; j++) s[j] = (f32x4){0.f, 0.f, 0.f, 0.f};
    #pragma unroll
    for (int j = 0; j < 5; j++) {
      s16x8 kf0 = *(const s16x8*)&kls[(j * 16 + r) * 72 + kg * 8];
      s16x8 kf1 = *(const s16x8*)&kls[(j * 16 + r) * 72 + kg * 8 + 32];
      s[j] = __builtin_amdgcn_mfma_f32_16x16x32_bf16(qf0, kf0, s[j], 0, 0, 0);
      s[j] = __builtin_amdgcn_mfma_f32_16x16x32_bf16(qf1, kf1, s[j], 0, 0, 0);
    }
    // softmax: lane holds rows kg*4+rr (rr=0..3), col t=j*16+r
    float st[5][4];
    float mx[4] = {-3e38f, -3e38f, -3e38f, -3e38f};
    #pragma unroll
    for (int j = 0; j < 5; j++) {
      bool valid = (j * 16 + r) < 77;
      #pragma unroll
      for (int rr = 0; rr < 4; rr++) {
        float v = valid ? s[j][rr] * 0.125f : -3e38f;
        st[j][rr] = v;
        mx[rr] = fmaxf(mx[rr], v);
      }
    }
    #pragma unroll
    for (int m = 1; m < 16; m <<= 1)
      #pragma unroll
      for (int rr = 0; rr < 4; rr++)
        mx[rr] = fmaxf(mx[rr], __shfl_xor(mx[rr], m, 64));
    float sm[4] = {0.f, 0.f, 0.f, 0.f};
    #pragma unroll
    for (int j = 0; j < 5; j++)
      #pragma unroll
      for (int rr = 0; rr < 4; rr++) {
        float e = __expf(st[j][rr] - mx[rr]);
        st[j][rr] = e;
        sm[rr] += e;
      }
    #pragma unroll
    for (int m = 1; m < 16; m <<= 1)
      #pragma unroll
      for (int rr = 0; rr < 4; rr++)
        sm[rr] += __shfl_xor(sm[rr], m, 64);
    float rinv[4];
    #pragma unroll
    for (int rr = 0; rr < 4; rr++) rinv[rr] = 1.f / sm[rr];

    // normalized w -> pls (for PV) and wAll (bf16 scatter)
    #pragma unroll
    for (int j = 0; j < 5; j++) {
      int t = j * 16 + r;
      #pragma unroll
      for (int rr = 0; rr < 4; rr++) {
        short wb = f2b(st[j][rr] * rinv[rr]);
        pls[wave][(kg * 4 + rr) * 104 + t] = wb;
        int row = m0 + kg * 4 + rr;
        if (row < 196 && t < 77)
          wAll[((size_t)bh * NP + row) * 77 + t] = wb;
      }
    }
    asm volatile("s_waitcnt lgkmcnt(0)" ::: "memory");
    __builtin_amdgcn_sched_barrier(0);

    // PV: A = w tile (rows=q-rows, k=t), B = V^T frags
    s16x8 pf[3];
    #pragma unroll
    for (int kk = 0; kk < 3; kk++)
      pf[kk] = *(const s16x8*)&pls[wave][r * 104 + kg * 8 + kk * 32];
    f32x4 o[4];
    #pragma unroll
    for (int jd = 0; jd < 4; jd++) o[jd] = (f32x4){0.f, 0.f, 0.f, 0.f};
    #pragma unroll
    for (int kk = 0; kk < 3; kk++)
      #pragma unroll
      for (int jd = 0; jd < 4; jd++)
        o[jd] = __builtin_amdgcn_mfma_f32_16x16x32_bf16(pf[kk], vf[jd][kk], o[jd], 0, 0, 0);
    #pragma unroll
    for (int jd = 0; jd < 4; jd++)
      #pragma unroll
      for (int rr = 0; rr < 4; rr++) {
        int row = m0 + kg * 4 + rr;
        if (row < 196)
          attnB[((size_t)(b * NP + row)) * 512 + h * 64 + jd * 16 + r] = f2b(o[jd][rr]);
      }
  }
}

// ---------- mean over heads of attention weights ----------
__global__ void meanw_kernel(const short* __restrict__ w_all, float* __restrict__ outW) {
  int i = blockIdx.x * 256 + threadIdx.x;
  if (i >= BATCH * NP * TL) return;
  int b = i / (NP * TL);
  int r = i - b * (NP * TL);
  float s = 0.f;
  #pragma unroll
  for (int h = 0; h < 8; h++) s += b2f(w_all[((size_t)(b * 8 + h)) * (NP * TL) + r]);
  outW[i] = s * 0.125f;
}

// ---------- partial row sums for means ----------
__global__ __launch_bounds__(256)
void avg_partial(const float* __restrict__ oAttn, const float* __restrict__ oPtxt,
                 float* __restrict__ partA, float* __restrict__ partC) {
  int b = blockIdx.x, s = blockIdx.y;
  int c0 = threadIdx.x * 2;
  float a0 = 0.f, a1 = 0.f;
  int r0 = s * 25, r1 = r0 + 25; if (r1 > 196) r1 = 196;
  const float* pa = oAttn + (size_t)b * NP * 512;
  for (int rI = r0; rI < r1; rI++) {
    a0 += pa[(size_t)rI * 512 + c0];
    a1 += pa[(size_t)rI * 512 + c0 + 1];
  }
  partA[((size_t)b * 8 + s) * 512 + c0] = a0;
  partA[((size_t)b * 8 + s) * 512 + c0 + 1] = a1;
  float t0 = 0.f, t1 = 0.f;
  int q0 = s * 10, q1 = q0 + 10; if (q1 > 77) q1 = 77;
  const float* pt = oPtxt + (size_t)b * TL * 512;
  for (int rI = q0; rI < q1; rI++) {
    t0 += pt[(size_t)rI * 512 + c0];
    t1 += pt[(size_t)rI * 512 + c0 + 1];
  }
  partC[((size_t)b * 8 + s) * 512 + c0] = t0;
  partC[((size_t)b * 8 + s) * 512 + c0 + 1] = t1;
}

// ---------- finalize means + l2 normalize ----------
__global__ __launch_bounds__(256)
void avg_final(const float* __restrict__ partA, const float* __restrict__ partC,
               float* __restrict__ oAvg, float* __restrict__ oCls,
               float* __restrict__ normA, float* __restrict__ normC) {
  int b = blockIdx.x;
  int c0 = threadIdx.x * 2;
  float a0 = 0.f, a1 = 0.f, t0 = 0.f, t1 = 0.f;
  for (int s = 0; s < 8; s++) {
    a0 += partA[((size_t)b * 8 + s) * 512 + c0];
    a1 += partA[((size_t)b * 8 + s) * 512 + c0 + 1];
    t0 += partC[((size_t)b * 8 + s) * 512 + c0];
    t1 += partC[((size_t)b * 8 + s) * 512 + c0 + 1];
  }
  a0 *= (1.f / 196.f); a1 *= (1.f / 196.f);
  t0 *= (1.f / 77.f);  t1 *= (1.f / 77.f);
  float sqA = a0 * a0 + a1 * a1, sqC = t0 * t0 + t1 * t1;
  #pragma unroll
  for (int off = 32; off > 0; off >>= 1) {
    sqA += __shfl_down(sqA, off, 64);
    sqC += __shfl_down(sqC, off, 64);
  }
  __shared__ float redA[4], redC[4];
  __shared__ float rAs, rCs;
  int wv = threadIdx.x >> 6, ln = threadIdx.x & 63;
  if (ln == 0) { redA[wv] = sqA; redC[wv] = sqC; }
  __syncthreads();
  if (threadIdx.x == 0) {
    float ta = redA[0] + redA[1] + redA[2] + redA[3];
    float tc = redC[0] + redC[1] + redC[2] + redC[3];
    rAs = 1.f / fmaxf(sqrtf(ta), 1e-8f);
    rCs = 1.f / fmaxf(sqrtf(tc), 1e-8f);
  }
  __syncthreads();
  float rA = rAs, rC = rCs;
  oAvg[(size_t)b * 512 + c0] = a0;       oAvg[(size_t)b * 512 + c0 + 1] = a1;
  oCls[(size_t)b * 512 + c0] = t0;       oCls[(size_t)b * 512 + c0 + 1] = t1;
  normA[(size_t)b * 512 + c0] = a0 * rA; normA[(size_t)b * 512 + c0 + 1] = a1 * rA;
  normC[(size_t)b * 512 + c0] = t0 * rC; normC[(size_t)b * 512 + c0 + 1] = t1 * rC;
}

// ---------- cosine similarity matrix 64x64 ----------
__global__ __launch_bounds__(256)
void score_kernel(const float* __restrict__ normA, const float* __restrict__ normC,
                  float* __restrict__ outScore) {
  int i = blockIdx.x;
  __shared__ float als[DM];
  __shared__ float part[256];
  for (int c = threadIdx.x; c < DM; c += 256) als[c] = normA[(size_t)i * DM + c];
  __syncthreads();
  int j = threadIdx.x & 63;
  int ch = threadIdx.x >> 6;
  float s = 0.f;
  for (int c = ch * 128; c < ch * 128 + 128; c++) s += als[c] * normC[(size_t)j * DM + c];
  part[threadIdx.x] = s;
  __syncthreads();
  if (threadIdx.x < 64) {
    outScore[(size_t)i * 64 + j] = part[j] + part[64 + j] + part[128 + j] + part[192 + j];
  }
}

// ---------- launcher ----------
extern "C" void kernel_launch(void* const* d_in, const int* in_sizes, int n_in,
                              void* d_out, int out_size, void* d_ws, size_t ws_size,
                              hipStream_t stream) {
  (void)in_sizes; (void)n_in; (void)out_size; (void)ws_size;
  const float* img = (const float*)d_in[0];
  const float* txt = (const float*)d_in[1];
  const float* Wi  = (const float*)d_in[2];
  const float* bi  = (const float*)d_in[3];
  const float* Wt  = (const float*)d_in[4];
  const float* bt  = (const float*)d_in[5];
  const float* Wq  = (const float*)d_in[6];
  const float* bq  = (const float*)d_in[7];
  const float* Wk  = (const float*)d_in[8];
  const float* bk  = (const float*)d_in[9];
  const float* Wv  = (const float*)d_in[10];
  const float* bv  = (const float*)d_in[11];
  const float* Wo  = (const float*)d_in[12];
  const float* bo  = (const float*)d_in[13];
  float* out = (float*)d_out;

  constexpr size_t MI = (size_t)BATCH * NP;   // 12544
  constexpr size_t MT = (size_t)BATCH * TL;   // 4928

  // region map (lifetime-aliased, total 73.33 MB):
  // R1 [0, 25.69M): aimg -> qBuf -> {normA, normC, partA, partC}
  // R2 [25.69M, 35.78M): textB -> kvBuf
  // R3 [35.78M, 48.63M): pimgB -> attnB
  // R4 [48.63M, 53.67M): ptxtB
  // R5 [53.67M, 57.87M): weights (wit,wtt,wqt,wkt,wvt,wot; wkt||wvt contiguous)
  // R6 [57.87M, 73.33M): wAll
  constexpr size_t O_R1    = 0;
  constexpr size_t O_TEXTB = MI * 1024 * 2;                    // 25,690,112
  constexpr size_t O_PIMGB = O_TEXTB + MT * 1024 * 2;          // 35,782,656
  constexpr size_t O_PTXTB = O_PIMGB + MI * 512 * 2;           // 48,627,712
  constexpr size_t O_WIT   = O_PTXTB + MT * 512 * 2;           // 53,673,984
  constexpr size_t O_WTT   = O_WIT + 1024 * 512 * 2;
  constexpr size_t O_WQT   = O_WTT + 1024 * 512 * 2;
  constexpr size_t O_WKT   = O_WQT + 512 * 512 * 2;
  constexpr size_t O_WVT   = O_WKT + 512 * 512 * 2;            // contiguous after WKT
  constexpr size_t O_WOT   = O_WVT + 512 * 512 * 2;
  constexpr size_t O_WALL  = O_WOT + 512 * 512 * 2;            // 57,868,288

  char* ws = (char*)d_ws;
  short* aimg  = (short*)(ws + O_R1);
  short* qBuf  = aimg;                                    // alias (aimg dead after pimg gemm)
  short* textB = (short*)(ws + O_TEXTB);
  short* kvBuf = textB;                                   // alias (textB dead after ptxt gemm)
  short* pimgB = (short*)(ws + O_PIMGB);
  short* attnB = pimgB;                                   // alias (pimgB dead after q gemm)
  short* ptxtB = (short*)(ws + O_PTXTB);
  short* wit   = (short*)(ws + O_WIT);
  short* wtt   = (short*)(ws + O_WTT);
  short* wqt   = (short*)(ws + O_WQT);
  short* wkt   = (short*)(ws + O_WKT);
  short* wvt   = (short*)(ws + O_WVT);
  short* wot   = (short*)(ws + O_WOT);
  short* wAll  = (short*)(ws + O_WALL);
  float* normA = (float*)(ws + O_R1);                     // after attn (qBuf dead)
  float* normC = (float*)(ws + O_R1 + 131072);
  float* partA = (float*)(ws + O_R1 + 262144);
  float* partC = (float*)(ws + O_R1 + 262144 + 1048576);

  // output layout (floats)
  float* oScore = out;                                    // 64*64
  float* oAttn  = out + 4096;                             // 64*196*512
  float* oW     = oAttn + MI * 512;                       // 64*196*77
  float* oAvg   = oW + (size_t)BATCH * NP * TL;           // 64*512
  float* oCls   = oAvg + (size_t)BATCH * DM;              // 64*512
  float* oPtxt  = oCls + (size_t)BATCH * DM;              // 64*77*512

  wtrans_kernel<<<dim3(32, 16, 6), 256, 0, stream>>>(Wi, Wt, Wq, Wk, Wv, Wo,
                                                     wit, wtt, wqt, wkt, wvt, wot);
  cast_f32_bf16<<<dim3(1024), 256, 0, stream>>>(txt, textB, (int)(MT * 1024 / 4));
  img_trans<<<dim3(32, 7, 64), 256, 0, stream>>>(img, aimg);

  gemm_bt<<<dim3(39, 4), 256, 0, stream>>>(textB, wtt, bt, bt, oPtxt, ptxtB, (int)MT, 1024, 512);
  gemm_bt<<<dim3(98, 4), 256, 0, stream>>>(aimg, wit, bi, bi, nullptr, pimgB, (int)MI, 1024, 512);
  gemm_bt<<<dim3(39, 8), 256, 0, stream>>>(ptxtB, wkt, bk, bv, nullptr, kvBuf, (int)MT, 512, 1024);
  gemm_bt<<<dim3(98, 4), 256, 0, stream>>>(pimgB, wqt, bq, bq, nullptr, qBuf, (int)MI, 512, 512);

  attn_kernel<<<dim3(512), 256, 0, stream>>>(qBuf, kvBuf, attnB, wAll);
  meanw_kernel<<<dim3((BATCH * NP * TL + 255) / 256), 256, 0, stream>>>(wAll, oW);

  gemm_bt<<<dim3(98, 4), 256, 0, stream>>>(attnB, wot, bo, bo, oAttn, nullptr, (int)MI, 512, 512);

  avg_partial<<<dim3(64, 8), 256, 0, stream>>>(oAttn, oPtxt, partA, partC);
  avg_final<<<dim3(64), 256, 0, stream>>>(partA, partC, oAvg, oCls, normA, normC);
  score_kernel<<<dim3(64), 256, 0, stream>>>(normA, normC, oScore);
}

// Round 3
// 187.264 us; speedup vs baseline: 1.7687x; 1.2847x over previous
//
#include <hip/hip_runtime.h>
#include <hip/hip_bf16.h>

// ---------- types ----------
typedef __attribute__((ext_vector_type(8))) short s16x8;
typedef __attribute__((ext_vector_type(4))) short s16x4;
typedef __attribute__((ext_vector_type(4))) float f32x4;

__device__ __forceinline__ float b2f(short s) {
  return __uint_as_float(((unsigned)(unsigned short)s) << 16);
}
__device__ __forceinline__ short f2b(float f) {
  unsigned u = __float_as_uint(f);
  unsigned r = u + 0x7fffu + ((u >> 16) & 1u);   // round-to-nearest-even
  return (short)(r >> 16);
}

// async global->LDS, 16B per lane; LDS dest = wave-uniform base + lane*16
__device__ __forceinline__ void gload16(const short* g, short* l) {
  __builtin_amdgcn_global_load_lds((const __attribute__((address_space(1))) void*)g,
                                   (__attribute__((address_space(3))) void*)l, 16, 0, 0);
}

// ---------- problem constants ----------
#define BATCH 64
#define NP    196
#define TL    77
#define DM    512
#define CIMG  1024

// ---------- weight transpose+cast: W[K][512] f32 -> WT[512][K] bf16 ----------
__global__ __launch_bounds__(256)
void wtrans_kernel(const float* __restrict__ Wi, const float* __restrict__ Wt,
                   const float* __restrict__ Wq, const float* __restrict__ Wk,
                   const float* __restrict__ Wv, const float* __restrict__ Wo,
                   short* __restrict__ WiT, short* __restrict__ WtT,
                   short* __restrict__ WqT, short* __restrict__ WkT,
                   short* __restrict__ WvT, short* __restrict__ WoT) {
  int z = blockIdx.z;
  const float* W; short* WT; int K;
  switch (z) {
    case 0: W = Wi; WT = WiT; K = 1024; break;
    case 1: W = Wt; WT = WtT; K = 1024; break;
    case 2: W = Wq; WT = WqT; K = 512;  break;
    case 3: W = Wk; WT = WkT; K = 512;  break;
    case 4: W = Wv; WT = WvT; K = 512;  break;
    default: W = Wo; WT = WoT; K = 512; break;
  }
  int k0 = blockIdx.x * 32, n0 = blockIdx.y * 32;
  if (k0 >= K) return;
  __shared__ float tile[32][33];
  int tx = threadIdx.x & 31, ty = threadIdx.x >> 5;   // ty 0..7
  #pragma unroll
  for (int i = 0; i < 4; i++) {
    int k = k0 + ty + i * 8;
    tile[ty + i * 8][tx] = W[(size_t)k * 512 + n0 + tx];
  }
  __syncthreads();
  #pragma unroll
  for (int i = 0; i < 4; i++) {
    int n = n0 + ty + i * 8;
    WT[(size_t)n * K + k0 + tx] = f2b(tile[tx][ty + i * 8]);
  }
}

// ---------- f32 -> bf16 cast (vectorized) ----------
__global__ void cast_f32_bf16(const float* __restrict__ in, short* __restrict__ out, int n4) {
  int stride = gridDim.x * blockDim.x;
  for (int i = blockIdx.x * blockDim.x + threadIdx.x; i < n4; i += stride) {
    float4 v = ((const float4*)in)[i];
    s16x4 o;
    o[0] = f2b(v.x); o[1] = f2b(v.y); o[2] = f2b(v.z); o[3] = f2b(v.w);
    ((s16x4*)out)[i] = o;
  }
}

// ---------- image transpose: [64][1024][196] f32 -> [64][196][1024] bf16 ----------
__global__ __launch_bounds__(256)
void img_trans(const float* __restrict__ img, short* __restrict__ out) {
  int b = blockIdx.z;
  int c0 = blockIdx.x * 32;
  int n0 = blockIdx.y * 32;
  __shared__ float tile[32][33];
  int tx = threadIdx.x & 31, ty = threadIdx.x >> 5;
  const float* ib = img + (size_t)b * CIMG * NP;
  #pragma unroll
  for (int i = 0; i < 4; i++) {
    int c = c0 + ty + i * 8, n = n0 + tx;
    tile[ty + i * 8][tx] = (n < NP) ? ib[(size_t)c * NP + n] : 0.f;
  }
  __syncthreads();
  short* ob = out + (size_t)b * NP * CIMG;
  #pragma unroll
  for (int i = 0; i < 4; i++) {
    int n = n0 + ty + i * 8;
    if (n < NP) ob[(size_t)n * CIMG + c0 + tx] = f2b(tile[tx][ty + i * 8]);
  }
}

// ---------- MFMA GEMM: C[M,N] = A[M,K](bf16) x BT[N,K]^T + bias ----------
// BM=64, BN=128, BK=64, 4 waves (2x2, each 32x64), double-buffered LDS with
// global_load_lds prefetch (2-phase). XOR-swizzled LDS: linear dest +
// inverse-swizzled global source col + swizzled read (rule #21 / T2).
// Requires: M%64==0, N%128==0, K%64==0.
__global__ __launch_bounds__(256)
void gemm_bt(const short* __restrict__ A, const short* __restrict__ BT,
             const float* __restrict__ bias, const float* __restrict__ bias2,
             float* __restrict__ outF, short* __restrict__ outB,
             int M, int K, int N) {
  __shared__ __align__(16) short As[2][64 * 64];
  __shared__ __align__(16) short Bs[2][128 * 64];
  int bm = blockIdx.x * 64, bn = blockIdx.y * 128;
  int tid = threadIdx.x, wave = tid >> 6, lane = tid & 63;
  int r = lane & 15, kg = lane >> 4, rr7 = r & 7;
  int wr = (wave >> 1) * 32, wc = (wave & 1) * 64;
  int l8 = lane >> 3, g8 = lane & 7;
  int scol = ((g8 ^ l8) << 3);          // swizzled source k-offset (elems)
  const short* gA = A + (size_t)(bm + wave * 16 + l8) * K + scol;
  const short* gB = BT + (size_t)(bn + wave * 32 + l8) * K + scol;

  f32x4 acc[2][4];
  #pragma unroll
  for (int i = 0; i < 2; i++)
    #pragma unroll
    for (int j = 0; j < 4; j++) acc[i][j] = (f32x4){0.f, 0.f, 0.f, 0.f};

  auto stage = [&](int buf, int k0) {
    #pragma unroll
    for (int j = 0; j < 2; j++)
      gload16(gA + (size_t)(j * 8) * K + k0, &As[buf][(wave * 16 + j * 8) * 64]);
    #pragma unroll
    for (int j = 0; j < 4; j++)
      gload16(gB + (size_t)(j * 8) * K + k0, &Bs[buf][(wave * 32 + j * 8) * 64]);
  };
  auto compute = [&](int buf) {
    s16x8 af[2][2], bf[4][2];
    #pragma unroll
    for (int ks = 0; ks < 2; ks++) {
      int gsw = (((ks << 2) + kg) ^ rr7) << 3;   // swizzled granule (elems)
      #pragma unroll
      for (int i = 0; i < 2; i++)
        af[i][ks] = *(const s16x8*)&As[buf][(wr + i * 16 + r) * 64 + gsw];
      #pragma unroll
      for (int j = 0; j < 4; j++)
        bf[j][ks] = *(const s16x8*)&Bs[buf][(wc + j * 16 + r) * 64 + gsw];
    }
    #pragma unroll
    for (int ks = 0; ks < 2; ks++)
      #pragma unroll
      for (int i = 0; i < 2; i++)
        #pragma unroll
        for (int j = 0; j < 4; j++)
          acc[i][j] = __builtin_amdgcn_mfma_f32_16x16x32_bf16(af[i][ks], bf[j][ks], acc[i][j], 0, 0, 0);
  };

  stage(0, 0);
  __syncthreads();                       // drains vmcnt(0)
  int nt = K >> 6, cur = 0;
  for (int t = 0; t < nt; t++) {
    if (t + 1 < nt) stage(cur ^ 1, (t + 1) << 6);   // prefetch next tile
    __builtin_amdgcn_sched_barrier(0);               // keep issue-early
    compute(cur);
    if (t + 1 < nt) { __syncthreads(); cur ^= 1; }   // next tile ready
  }

  // epilogue: C/D layout col=lane&15, row=(lane>>4)*4+reg
  #pragma unroll
  for (int i = 0; i < 2; i++) {
    #pragma unroll
    for (int rr = 0; rr < 4; rr++) {
      int row = bm + wr + i * 16 + kg * 4 + rr;
      #pragma unroll
      for (int j = 0; j < 4; j++) {
        int col = bn + wc + j * 16 + r;
        float bval = (col < 512) ? bias[col] : bias2[col - 512];
        float v = acc[i][j][rr] + bval;
        if (outF) outF[(size_t)row * N + col] = v;
        if (outB) outB[(size_t)row * N + col] = f2b(v);
      }
    }
  }
}

// ---------- MFMA attention: one block per (b,h), 4 waves ----------
// kvB layout: [B*TL][1024] bf16, cols 0..511 = k, 512..1023 = v
__global__ __launch_bounds__(256)
void attn_kernel(const short* __restrict__ qB, const short* __restrict__ kvB,
                 short* __restrict__ attnB, short* __restrict__ wAll) {
  __shared__ short kls[80 * 72];        // K rows padded to 80, stride 72 (2-way)
  __shared__ short vtls[64 * 104];      // V^T [d][t], t<96 used, stride 104 (2-way)
  __shared__ short pls[4][16 * 104];    // per-wave P tile [16 rows][t]
  int bh = blockIdx.x, b = bh >> 3, h = bh & 7;
  int tid = threadIdx.x, wave = tid >> 6, lane = tid & 63;
  int r = lane & 15, kg = lane >> 4;

  // zero pls (cols 80..95 must stay zero for PV K-padding)
  for (int i = lane; i < 208; i += 64)
    *(s16x8*)&pls[wave][i * 8] = (s16x8){0, 0, 0, 0, 0, 0, 0, 0};

  // stage K -> kls (rows >=77 zero)
  for (int idx = tid; idx < 80 * 8; idx += 256) {
    int t = idx >> 3, c8 = (idx & 7) << 3;
    s16x8 v = (s16x8){0, 0, 0, 0, 0, 0, 0, 0};
    if (t < 77) v = *(const s16x8*)&kvB[((size_t)(b * TL + t)) * 1024 + h * 64 + c8];
    *(s16x8*)&kls[t * 72 + c8] = v;
  }
  // stage V^T -> vtls[d][t] (t>=77 zero)
  for (int idx = tid; idx < 64 * 12; idx += 256) {
    int d = idx & 63, t8 = idx >> 6;    // t8 0..11 covers t<96
    s16x8 v;
    #pragma unroll
    for (int j = 0; j < 8; j++) {
      int t = t8 * 8 + j;
      v[j] = (t < 77) ? kvB[((size_t)(b * TL + t)) * 1024 + 512 + h * 64 + d] : (short)0;
    }
    *(s16x8*)&vtls[d * 104 + t8 * 8] = v;
  }
  __syncthreads();

  // V B-fragments in registers (reused across m-frags)
  s16x8 vf[4][3];
  #pragma unroll
  for (int jd = 0; jd < 4; jd++)
    #pragma unroll
    for (int kk = 0; kk < 3; kk++)
      vf[jd][kk] = *(const s16x8*)&vtls[(jd * 16 + r) * 104 + kg * 8 + kk * 32];

  for (int mf = wave; mf < 13; mf += 4) {
    int m0 = mf * 16;
    int qrow = m0 + r; if (qrow > 195) qrow = 195;
    const short* qp = qB + ((size_t)(b * NP + qrow)) * 512 + h * 64 + kg * 8;
    s16x8 qf0 = *(const s16x8*)qp;
    s16x8 qf1 = *(const s16x8*)(qp + 32);

    f32x4 s[5];
    #pragma unroll
    for (int j = 0; j < 5; j++) s[j] = (f32x4){0.f, 0.f, 0.f, 0.f};
    #pragma unroll
    for (int j = 0; j < 5; j++) {
      s16x8 kf0 = *(const s16x8*)&kls[(j * 16 + r) * 72 + kg * 8];
      s16x8 kf1 = *(const s16x8*)&kls[(j * 16 + r) * 72 + kg * 8 + 32];
      s[j] = __builtin_amdgcn_mfma_f32_16x16x32_bf16(qf0, kf0, s[j], 0, 0, 0);
      s[j] = __builtin_amdgcn_mfma_f32_16x16x32_bf16(qf1, kf1, s[j], 0, 0, 0);
    }
    // softmax: lane holds rows kg*4+rr (rr=0..3), col t=j*16+r
    float st[5][4];
    float mx[4] = {-3e38f, -3e38f, -3e38f, -3e38f};
    #pragma unroll
    for (int j = 0; j < 5; j++) {
      bool valid = (j * 16 + r) < 77;
      #pragma unroll
      for (int rr = 0; rr < 4; rr++) {
        float v = valid ? s[j][rr] * 0.125f : -3e38f;
        st[j][rr] = v;
        mx[rr] = fmaxf(mx[rr], v);
      }
    }
    #pragma unroll
    for (int m = 1; m < 16; m <<= 1)
      #pragma unroll
      for (int rr = 0; rr < 4; rr++)
        mx[rr] = fmaxf(mx[rr], __shfl_xor(mx[rr], m, 64));
    float sm[4] = {0.f, 0.f, 0.f, 0.f};
    #pragma unroll
    for (int j = 0; j < 5; j++)
      #pragma unroll
      for (int rr = 0; rr < 4; rr++) {
        float e = __expf(st[j][rr] - mx[rr]);
        st[j][rr] = e;
        sm[rr] += e;
      }
    #pragma unroll
    for (int m = 1; m < 16; m <<= 1)
      #pragma unroll
      for (int rr = 0; rr < 4; rr++)
        sm[rr] += __shfl_xor(sm[rr], m, 64);
    float rinv[4];
    #pragma unroll
    for (int rr = 0; rr < 4; rr++) rinv[rr] = 1.f / sm[rr];

    // normalized w -> pls (for PV) and wAll (bf16 scatter)
    #pragma unroll
    for (int j = 0; j < 5; j++) {
      int t = j * 16 + r;
      #pragma unroll
      for (int rr = 0; rr < 4; rr++) {
        short wb = f2b(st[j][rr] * rinv[rr]);
        pls[wave][(kg * 4 + rr) * 104 + t] = wb;
        int row = m0 + kg * 4 + rr;
        if (row < 196 && t < 77)
          wAll[((size_t)bh * NP + row) * 77 + t] = wb;
      }
    }
    asm volatile("s_waitcnt lgkmcnt(0)" ::: "memory");
    __builtin_amdgcn_sched_barrier(0);

    // PV: A = w tile (rows=q-rows, k=t), B = V^T frags
    s16x8 pf[3];
    #pragma unroll
    for (int kk = 0; kk < 3; kk++)
      pf[kk] = *(const s16x8*)&pls[wave][r * 104 + kg * 8 + kk * 32];
    f32x4 o[4];
    #pragma unroll
    for (int jd = 0; jd < 4; jd++) o[jd] = (f32x4){0.f, 0.f, 0.f, 0.f};
    #pragma unroll
    for (int kk = 0; kk < 3; kk++)
      #pragma unroll
      for (int jd = 0; jd < 4; jd++)
        o[jd] = __builtin_amdgcn_mfma_f32_16x16x32_bf16(pf[kk], vf[jd][kk], o[jd], 0, 0, 0);
    #pragma unroll
    for (int jd = 0; jd < 4; jd++)
      #pragma unroll
      for (int rr = 0; rr < 4; rr++) {
        int row = m0 + kg * 4 + rr;
        if (row < 196)
          attnB[((size_t)(b * NP + row)) * 512 + h * 64 + jd * 16 + r] = f2b(o[jd][rr]);
      }
  }
}

// ---------- mean over heads of attention weights ----------
__global__ void meanw_kernel(const short* __restrict__ w_all, float* __restrict__ outW) {
  int i = blockIdx.x * 256 + threadIdx.x;
  if (i >= BATCH * NP * TL) return;
  int b = i / (NP * TL);
  int r = i - b * (NP * TL);
  float s = 0.f;
  #pragma unroll
  for (int h = 0; h < 8; h++) s += b2f(w_all[((size_t)(b * 8 + h)) * (NP * TL) + r]);
  outW[i] = s * 0.125f;
}

// ---------- partial row sums for means ----------
__global__ __launch_bounds__(256)
void avg_partial(const float* __restrict__ oAttn, const float* __restrict__ oPtxt,
                 float* __restrict__ partA, float* __restrict__ partC) {
  int b = blockIdx.x, s = blockIdx.y;
  int c0 = threadIdx.x * 2;
  float a0 = 0.f, a1 = 0.f;
  int r0 = s * 25, r1 = r0 + 25; if (r1 > 196) r1 = 196;
  const float* pa = oAttn + (size_t)b * NP * 512;
  for (int rI = r0; rI < r1; rI++) {
    a0 += pa[(size_t)rI * 512 + c0];
    a1 += pa[(size_t)rI * 512 + c0 + 1];
  }
  partA[((size_t)b * 8 + s) * 512 + c0] = a0;
  partA[((size_t)b * 8 + s) * 512 + c0 + 1] = a1;
  float t0 = 0.f, t1 = 0.f;
  int q0 = s * 10, q1 = q0 + 10; if (q1 > 77) q1 = 77;
  const float* pt = oPtxt + (size_t)b * TL * 512;
  for (int rI = q0; rI < q1; rI++) {
    t0 += pt[(size_t)rI * 512 + c0];
    t1 += pt[(size_t)rI * 512 + c0 + 1];
  }
  partC[((size_t)b * 8 + s) * 512 + c0] = t0;
  partC[((size_t)b * 8 + s) * 512 + c0 + 1] = t1;
}

// ---------- finalize means + l2 normalize ----------
__global__ __launch_bounds__(256)
void avg_final(const float* __restrict__ partA, const float* __restrict__ partC,
               float* __restrict__ oAvg, float* __restrict__ oCls,
               float* __restrict__ normA, float* __restrict__ normC) {
  int b = blockIdx.x;
  int c0 = threadIdx.x * 2;
  float a0 = 0.f, a1 = 0.f, t0 = 0.f, t1 = 0.f;
  for (int s = 0; s < 8; s++) {
    a0 += partA[((size_t)b * 8 + s) * 512 + c0];
    a1 += partA[((size_t)b * 8 + s) * 512 + c0 + 1];
    t0 += partC[((size_t)b * 8 + s) * 512 + c0];
    t1 += partC[((size_t)b * 8 + s) * 512 + c0 + 1];
  }
  a0 *= (1.f / 196.f); a1 *= (1.f / 196.f);
  t0 *= (1.f / 77.f);  t1 *= (1.f / 77.f);
  float sqA = a0 * a0 + a1 * a1, sqC = t0 * t0 + t1 * t1;
  #pragma unroll
  for (int off = 32; off > 0; off >>= 1) {
    sqA += __shfl_down(sqA, off, 64);
    sqC += __shfl_down(sqC, off, 64);
  }
  __shared__ float redA[4], redC[4];
  __shared__ float rAs, rCs;
  int wv = threadIdx.x >> 6, ln = threadIdx.x & 63;
  if (ln == 0) { redA[wv] = sqA; redC[wv] = sqC; }
  __syncthreads();
  if (threadIdx.x == 0) {
    float ta = redA[0] + redA[1] + redA[2] + redA[3];
    float tc = redC[0] + redC[1] + redC[2] + redC[3];
    rAs = 1.f / fmaxf(sqrtf(ta), 1e-8f);
    rCs = 1.f / fmaxf(sqrtf(tc), 1e-8f);
  }
  __syncthreads();
  float rA = rAs, rC = rCs;
  oAvg[(size_t)b * 512 + c0] = a0;       oAvg[(size_t)b * 512 + c0 + 1] = a1;
  oCls[(size_t)b * 512 + c0] = t0;       oCls[(size_t)b * 512 + c0 + 1] = t1;
  normA[(size_t)b * 512 + c0] = a0 * rA; normA[(size_t)b * 512 + c0 + 1] = a1 * rA;
  normC[(size_t)b * 512 + c0] = t0 * rC; normC[(size_t)b * 512 + c0 + 1] = t1 * rC;
}

// ---------- cosine similarity matrix 64x64 ----------
__global__ __launch_bounds__(256)
void score_kernel(const float* __restrict__ normA, const float* __restrict__ normC,
                  float* __restrict__ outScore) {
  int i = blockIdx.x;
  __shared__ float als[DM];
  __shared__ float part[256];
  for (int c = threadIdx.x; c < DM; c += 256) als[c] = normA[(size_t)i * DM + c];
  __syncthreads();
  int j = threadIdx.x & 63;
  int ch = threadIdx.x >> 6;
  float s = 0.f;
  for (int c = ch * 128; c < ch * 128 + 128; c++) s += als[c] * normC[(size_t)j * DM + c];
  part[threadIdx.x] = s;
  __syncthreads();
  if (threadIdx.x < 64) {
    outScore[(size_t)i * 64 + j] = part[j] + part[64 + j] + part[128 + j] + part[192 + j];
  }
}

// ---------- launcher ----------
extern "C" void kernel_launch(void* const* d_in, const int* in_sizes, int n_in,
                              void* d_out, int out_size, void* d_ws, size_t ws_size,
                              hipStream_t stream) {
  (void)in_sizes; (void)n_in; (void)out_size; (void)ws_size;
  const float* img = (const float*)d_in[0];
  const float* txt = (const float*)d_in[1];
  const float* Wi  = (const float*)d_in[2];
  const float* bi  = (const float*)d_in[3];
  const float* Wt  = (const float*)d_in[4];
  const float* bt  = (const float*)d_in[5];
  const float* Wq  = (const float*)d_in[6];
  const float* bq  = (const float*)d_in[7];
  const float* Wk  = (const float*)d_in[8];
  const float* bk  = (const float*)d_in[9];
  const float* Wv  = (const float*)d_in[10];
  const float* bv  = (const float*)d_in[11];
  const float* Wo  = (const float*)d_in[12];
  const float* bo  = (const float*)d_in[13];
  float* out = (float*)d_out;

  constexpr size_t MI = (size_t)BATCH * NP;   // 12544
  constexpr size_t MT = (size_t)BATCH * TL;   // 4928

  // region map (lifetime-aliased, total 73.33 MB)
  constexpr size_t O_R1    = 0;
  constexpr size_t O_TEXTB = MI * 1024 * 2;                    // 25,690,112
  constexpr size_t O_PIMGB = O_TEXTB + MT * 1024 * 2;          // 35,782,656
  constexpr size_t O_PTXTB = O_PIMGB + MI * 512 * 2;           // 48,627,712
  constexpr size_t O_WIT   = O_PTXTB + MT * 512 * 2;           // 53,673,984
  constexpr size_t O_WTT   = O_WIT + 1024 * 512 * 2;
  constexpr size_t O_WQT   = O_WTT + 1024 * 512 * 2;
  constexpr size_t O_WKT   = O_WQT + 512 * 512 * 2;
  constexpr size_t O_WVT   = O_WKT + 512 * 512 * 2;            // contiguous after WKT
  constexpr size_t O_WOT   = O_WVT + 512 * 512 * 2;
  constexpr size_t O_WALL  = O_WOT + 512 * 512 * 2;            // 57,868,288

  char* ws = (char*)d_ws;
  short* aimg  = (short*)(ws + O_R1);
  short* qBuf  = aimg;                                    // alias (aimg dead after q gemm reads? no: q gemm reads pimgB)
  short* textB = (short*)(ws + O_TEXTB);
  short* kvBuf = textB;                                   // alias (textB dead after ptxt gemm)
  short* pimgB = (short*)(ws + O_PIMGB);
  short* attnB = pimgB;                                   // alias (pimgB dead after q gemm)
  short* ptxtB = (short*)(ws + O_PTXTB);
  short* wit   = (short*)(ws + O_WIT);
  short* wtt   = (short*)(ws + O_WTT);
  short* wqt   = (short*)(ws + O_WQT);
  short* wkt   = (short*)(ws + O_WKT);
  short* wvt   = (short*)(ws + O_WVT);
  short* wot   = (short*)(ws + O_WOT);
  short* wAll  = (short*)(ws + O_WALL);
  float* normA = (float*)(ws + O_R1);                     // after attn (qBuf dead)
  float* normC = (float*)(ws + O_R1 + 131072);
  float* partA = (float*)(ws + O_R1 + 262144);
  float* partC = (float*)(ws + O_R1 + 262144 + 1048576);

  // output layout (floats)
  float* oScore = out;                                    // 64*64
  float* oAttn  = out + 4096;                             // 64*196*512
  float* oW     = oAttn + MI * 512;                       // 64*196*77
  float* oAvg   = oW + (size_t)BATCH * NP * TL;           // 64*512
  float* oCls   = oAvg + (size_t)BATCH * DM;              // 64*512
  float* oPtxt  = oCls + (size_t)BATCH * DM;              // 64*77*512

  wtrans_kernel<<<dim3(32, 16, 6), 256, 0, stream>>>(Wi, Wt, Wq, Wk, Wv, Wo,
                                                     wit, wtt, wqt, wkt, wvt, wot);
  cast_f32_bf16<<<dim3(1024), 256, 0, stream>>>(txt, textB, (int)(MT * 1024 / 4));
  img_trans<<<dim3(32, 7, 64), 256, 0, stream>>>(img, aimg);

  gemm_bt<<<dim3(77, 4), 256, 0, stream>>>(textB, wtt, bt, bt, oPtxt, ptxtB, (int)MT, 1024, 512);
  gemm_bt<<<dim3(196, 4), 256, 0, stream>>>(aimg, wit, bi, bi, nullptr, pimgB, (int)MI, 1024, 512);
  gemm_bt<<<dim3(77, 8), 256, 0, stream>>>(ptxtB, wkt, bk, bv, nullptr, kvBuf, (int)MT, 512, 1024);
  gemm_bt<<<dim3(196, 4), 256, 0, stream>>>(pimgB, wqt, bq, bq, nullptr, qBuf, (int)MI, 512, 512);

  attn_kernel<<<dim3(512), 256, 0, stream>>>(qBuf, kvBuf, attnB, wAll);
  meanw_kernel<<<dim3((BATCH * NP * TL + 255) / 256), 256, 0, stream>>>(wAll, oW);

  gemm_bt<<<dim3(196, 4), 256, 0, stream>>>(attnB, wot, bo, bo, oAttn, nullptr, (int)MI, 512, 512);

  avg_partial<<<dim3(64, 8), 256, 0, stream>>>(oAttn, oPtxt, partA, partC);
  avg_final<<<dim3(64), 256, 0, stream>>>(partA, partC, oAvg, oCls, normA, normC);
  score_kernel<<<dim3(64), 256, 0, stream>>>(normA, normC, oScore);
}